// Round 1
// baseline (806.322 us; speedup 1.0000x reference)
//
#include <hip/hip_runtime.h>

// Sparse convolution: out[out_map[k,m]] += input[in_map[k,m]] @ kernel[k]  (+ bias)
// N=262144 voxels, M=131072 pairs/offset, K=27 offsets, C_in=C_out=32, fp32.

constexpr int N_VOX   = 262144;
constexpr int M_PAIRS = 131072;
constexpr int K_VOL   = 27;
constexpr int C       = 32;

constexpr int BLOCKS_PER_K    = 64;
constexpr int PAIRS_PER_CHUNK = M_PAIRS / BLOCKS_PER_K;  // 2048
constexpr int PAIRS_PER_ITER  = 8;                       // 256 threads / 32 lanes-per-pair

// out[n][c] = bias[c]  (harness poisons d_out before every launch)
__global__ __launch_bounds__(256) void init_out_kernel(const float* __restrict__ bias,
                                                       float* __restrict__ out) {
    const int total  = N_VOX * C;
    const int stride = gridDim.x * 256;
    // idx % 32 == threadIdx.x % 32 for all iterations (stride multiple of 32)
    const float b = bias[threadIdx.x & (C - 1)];
    for (int idx = blockIdx.x * 256 + threadIdx.x; idx < total; idx += stride) {
        out[idx] = b;
    }
}

__global__ __launch_bounds__(256) void spconv_kernel(
    const float* __restrict__ input,
    const float* __restrict__ kernel,
    const int*   __restrict__ in_map,
    const int*   __restrict__ out_map,
    float*       __restrict__ out)
{
    const int k     = blockIdx.x / BLOCKS_PER_K;
    const int chunk = blockIdx.x % BLOCKS_PER_K;
    const int tid   = threadIdx.x;
    const int c     = tid & 31;          // output channel owned by this lane
    const int gbase = tid & 32;          // 32-lane group base within the wave

    // Each lane holds kernel[k][:, c] in registers (loaded once per block).
    float kr[C];
    const float* kptr = kernel + k * C * C;
    #pragma unroll
    for (int i = 0; i < C; ++i) kr[i] = kptr[i * C + c];

    const int* imap = in_map  + k * M_PAIRS + chunk * PAIRS_PER_CHUNK;
    const int* omap = out_map + k * M_PAIRS + chunk * PAIRS_PER_CHUNK;
    const int pl = tid >> 5;             // which pair within the 8-pair iteration

    for (int pb = pl; pb < PAIRS_PER_CHUNK; pb += PAIRS_PER_ITER) {
        const int in_row  = imap[pb];
        const int out_row = omap[pb];

        // Coalesced 128B gather of the input row: lane c fetches element c.
        const float x = input[in_row * C + c];

        // out[c] = sum_i input[i] * kernel[i][c]; broadcast input[i] via shfl.
        float acc = 0.f;
        #pragma unroll
        for (int i = 0; i < C; ++i) {
            acc = fmaf(__shfl(x, gbase + i, 64), kr[i], acc);
        }

        atomicAdd(&out[out_row * C + c], acc);
    }
}

extern "C" void kernel_launch(void* const* d_in, const int* in_sizes, int n_in,
                              void* d_out, int out_size, void* d_ws, size_t ws_size,
                              hipStream_t stream) {
    const float* input  = (const float*)d_in[0];
    const float* kernel = (const float*)d_in[1];
    const float* bias   = (const float*)d_in[2];
    const int*   in_map = (const int*)d_in[3];
    const int*   out_map= (const int*)d_in[4];
    float* out = (float*)d_out;

    init_out_kernel<<<4096, 256, 0, stream>>>(bias, out);
    spconv_kernel<<<K_VOL * BLOCKS_PER_K, 256, 0, stream>>>(input, kernel, in_map, out_map, out);
}